// Round 7
// baseline (753.710 us; speedup 1.0000x reference)
//
#include <hip/hip_runtime.h>
#include <hip/hip_bf16.h>

#define N_PTS 65536
#define BATCH 2
#define KNN   16
#define NBLK_STATS 512

typedef float float4n __attribute__((ext_vector_type(4)));

__device__ __forceinline__ int tri(int i, int j) { // i<=j, 7x7 upper triangle
    return i * 7 - (i * (i - 1)) / 2 + (j - i);
}

// ---- Pass 1: moments of v=(cx,cy,cz,nx,ny,nz,d); per-block partials, no contended atomics ----
__global__ __launch_bounds__(256) void k_stats(const float* __restrict__ coords,
                                               const int* __restrict__ knn,
                                               const float* __restrict__ dist,
                                               float* __restrict__ stats_atomic,
                                               float* __restrict__ partials,
                                               int use_part) {
    int gid = blockIdx.x * 256 + threadIdx.x;   // one per (b,n), total B*N = 131072
    int b = gid >> 16;
    const float* cp = coords + (size_t)gid * 3;
    float cx = cp[0], cy = cp[1], cz = cp[2];
    const float* cb = coords + (size_t)b * (N_PTS * 3);
    const int* ip = knn + ((size_t)gid << 4);
    const float* dp = dist + ((size_t)gid << 4);

    float s[35];
#pragma unroll
    for (int i = 0; i < 35; i++) s[i] = 0.f;

    for (int k = 0; k < KNN; k++) {
        int idx = ip[k];
        const float* q = cb + (size_t)idx * 3;
        float v[7];
        v[0] = cx; v[1] = cy; v[2] = cz;
        v[3] = q[0]; v[4] = q[1]; v[5] = q[2];
        v[6] = dp[k];
        int t = 7;
#pragma unroll
        for (int i = 0; i < 7; i++) {
            s[i] += v[i];
#pragma unroll
            for (int j = i; j < 7; j++) { s[t] += v[i] * v[j]; t++; }
        }
    }

    __shared__ float red[4][35];
    int lane = threadIdx.x & 63;
    int wid  = threadIdx.x >> 6;
#pragma unroll
    for (int i = 0; i < 35; i++) {
        float v = s[i];
#pragma unroll
        for (int off = 32; off; off >>= 1) v += __shfl_xor(v, off);
        if (lane == 0) red[wid][i] = v;
    }
    __syncthreads();
    if (threadIdx.x < 35) {
        int i = threadIdx.x;
        float v = (red[0][i] + red[1][i]) + (red[2][i] + red[3][i]);
        if (use_part) partials[i * NBLK_STATS + blockIdx.x] = v;
        else          atomicAdd(&stats_atomic[i], v);   // 512 blocks x 35 only
    }
}

// ---- Prep: reduce partials, fold BN into per-channel affine w8 ----
__global__ __launch_bounds__(64) void k_prep(const float* __restrict__ W,
                                             const float* __restrict__ bias,
                                             const float* __restrict__ gamma,
                                             const float* __restrict__ beta,
                                             const float* __restrict__ stats_atomic,
                                             const float* __restrict__ partials,
                                             int use_part,
                                             float* __restrict__ w8) {
    __shared__ float sst[35];
    int t = threadIdx.x;
    if (t < 35) {
        if (use_part) {
            const float* p = partials + t * NBLK_STATS;
            float a0 = 0.f, a1 = 0.f, a2 = 0.f, a3 = 0.f;
            for (int j = 0; j < NBLK_STATS; j += 4) {
                a0 += p[j]; a1 += p[j + 1]; a2 += p[j + 2]; a3 += p[j + 3];
            }
            sst[t] = (a0 + a1) + (a2 + a3);
        } else {
            sst[t] = stats_atomic[t];
        }
    }
    __syncthreads();

    int o = t; // 0..63
    const float invM = 1.0f / (float)((size_t)BATCH * N_PTS * KNN);
    float m[7];
#pragma unroll
    for (int j = 0; j < 7; j++) m[j] = sst[j] * invM;
    const float* Wo = W + o * 10;
    float wv[7];
    wv[0] = Wo[0] + Wo[6]; wv[1] = Wo[1] + Wo[7]; wv[2] = Wo[2] + Wo[8];
    wv[3] = Wo[3] - Wo[6]; wv[4] = Wo[4] - Wo[7]; wv[5] = Wo[5] - Wo[8];
    wv[6] = Wo[9];
    float mean = bias[o];
#pragma unroll
    for (int j = 0; j < 7; j++) mean += wv[j] * m[j];
    float var = 0.f;
#pragma unroll
    for (int i = 0; i < 7; i++) {
#pragma unroll
        for (int j = 0; j < 7; j++) {
            int a = i < j ? i : j, c = i < j ? j : i;
            float cov = sst[7 + tri(a, c)] * invM - m[i] * m[j];
            var += wv[i] * wv[j] * cov;
        }
    }
    float s = gamma[o] * rsqrtf(var + 1e-6f);
    float sh = beta[o] - mean * s;        // out = s*x + sh, x = wv.v + b_o
#pragma unroll
    for (int j = 0; j < 7; j++) w8[o * 8 + j] = s * wv[j];
    w8[o * 8 + 7] = s * bias[o] + sh;     // fold bias into constant
}

// ---- Pass 2: x channels [B,0..63,N,K], f32 out, NT stores ----
__global__ __launch_bounds__(256) void k_x(const float* __restrict__ coords,
                                           const int* __restrict__ knn,
                                           const float* __restrict__ dist,
                                           const float* __restrict__ w8g,
                                           float* __restrict__ out) {
    __shared__ float w8[512];
    for (int i = threadIdx.x; i < 512; i += 256) w8[i] = w8g[i];
    __syncthreads();

    int gid = blockIdx.x * 256 + threadIdx.x;   // B*N*2 threads
    int h = gid & 1;
    int pp = gid >> 1;                           // b*N + n
    int b = pp >> 16;
    int n = pp & 0xFFFF;

    const float* cp = coords + (size_t)pp * 3;
    float cx = cp[0], cy = cp[1], cz = cp[2];
    const float* cb = coords + (size_t)b * (N_PTS * 3);
    const int* ip = knn + ((size_t)pp << 4) + (h << 3);
    const float* dp = dist + ((size_t)pp << 4) + (h << 3);

    int4 ia = *(const int4*)ip;
    int4 ib = *(const int4*)(ip + 4);
    float4 da = *(const float4*)dp;
    float4 db = *(const float4*)(dp + 4);
    int   idx[8] = {ia.x, ia.y, ia.z, ia.w, ib.x, ib.y, ib.z, ib.w};
    float dd[8]  = {da.x, da.y, da.z, da.w, db.x, db.y, db.z, db.w};
    float nx[8], ny[8], nz[8];
#pragma unroll
    for (int k = 0; k < 8; k++) {
        const float* q = cb + (size_t)idx[k] * 3;
        nx[k] = q[0]; ny[k] = q[1]; nz[k] = q[2];
    }

    size_t base = (((size_t)b * 128) * N_PTS + n) * KNN + (h << 3);
#pragma unroll 2
    for (int c = 0; c < 64; c++) {
        float4 wa = *reinterpret_cast<const float4*>(&w8[c << 3]);      // ds_read_b128
        float4 wb = *reinterpret_cast<const float4*>(&w8[(c << 3) + 4]);
        float s0 = fmaf(cx, wa.x, fmaf(cy, wa.y, fmaf(cz, wa.z, wb.w)));
        float x[8];
#pragma unroll
        for (int k = 0; k < 8; k++) {
            float v = fmaf(dd[k], wb.z, fmaf(nz[k], wb.y, fmaf(ny[k], wb.x, fmaf(nx[k], wa.w, s0))));
            x[k] = fmaxf(v, 0.f);
        }
        float* op = out + base + (size_t)c * (N_PTS * KNN);
        float4n v0 = {x[0], x[1], x[2], x[3]};
        float4n v1 = {x[4], x[5], x[6], x[7]};
        __builtin_nontemporal_store(v0, reinterpret_cast<float4n*>(op));
        __builtin_nontemporal_store(v1, reinterpret_cast<float4n*>(op + 4));
    }
}

// ---- Pass 3: feature broadcast [B,64..127,N,K], f32 out, NT stores ----
__global__ __launch_bounds__(256) void k_feat(const float* __restrict__ feat,
                                              float* __restrict__ out) {
    int gid = blockIdx.x * 256 + threadIdx.x;  // B*64*N*2 threads
    int h = gid & 1;
    int q = gid >> 1;                          // (b*64+f)*N + n
    float v = feat[q];
    int b = q >> 22;
    int f = (q >> 16) & 63;
    int n = q & 0xFFFF;
    size_t base = (((size_t)b * 128 + 64 + f) * N_PTS + n) * KNN + (h << 3);
    float4n vv = {v, v, v, v};
    __builtin_nontemporal_store(vv, reinterpret_cast<float4n*>(out + base));
    __builtin_nontemporal_store(vv, reinterpret_cast<float4n*>(out + base + 4));
}

extern "C" void kernel_launch(void* const* d_in, const int* in_sizes, int n_in,
                              void* d_out, int out_size, void* d_ws, size_t ws_size,
                              hipStream_t stream) {
    const float* coords   = (const float*)d_in[0];
    const float* features = (const float*)d_in[1];
    const int*   knn      = (const int*)d_in[2];
    const float* dist     = (const float*)d_in[3];
    const float* W        = (const float*)d_in[4];
    const float* bias     = (const float*)d_in[5];
    const float* gamma    = (const float*)d_in[6];
    const float* beta     = (const float*)d_in[7];
    float* out            = (float*)d_out;

    // ws layout: stats[64] | w8[512] | partials[35*512]
    float* stats    = (float*)d_ws;
    float* w8       = stats + 64;
    float* partials = w8 + 512;
    size_t need = (64 + 512 + 35 * NBLK_STATS) * sizeof(float);
    int use_part = (ws_size >= need) ? 1 : 0;

    (void)hipMemsetAsync(d_ws, 0, 64 * sizeof(float), stream);  // only atomic path needs it
    k_stats<<<NBLK_STATS, 256, 0, stream>>>(coords, knn, dist, stats, partials, use_part);
    k_prep<<<1, 64, 0, stream>>>(W, bias, gamma, beta, stats, partials, use_part, w8);
    // MEASUREMENT: k_x launched twice (idempotent). dur - 505us = t_kx.
    k_x<<<1024, 256, 0, stream>>>(coords, knn, dist, w8, out);
    k_x<<<1024, 256, 0, stream>>>(coords, knn, dist, w8, out);
    k_feat<<<65536, 256, 0, stream>>>(features, out);
}

// Round 8
// 377.547 us; speedup vs baseline: 1.9963x; 1.9963x over previous
//
#include <hip/hip_runtime.h>
#include <hip/hip_bf16.h>

#define N_PTS 65536
#define BATCH 2
#define KNN   16
#define NBLK_STATS 512

typedef float float4n __attribute__((ext_vector_type(4)));

__device__ __forceinline__ int tri(int i, int j) { // i<=j, 7x7 upper triangle
    return i * 7 - (i * (i - 1)) / 2 + (j - i);
}

// ---- Pass 1: moments of v=(cx,cy,cz,nx,ny,nz,d); per-block partials, no contended atomics ----
__global__ __launch_bounds__(256) void k_stats(const float* __restrict__ coords,
                                               const int* __restrict__ knn,
                                               const float* __restrict__ dist,
                                               float* __restrict__ stats_atomic,
                                               float* __restrict__ partials,
                                               int use_part) {
    int gid = blockIdx.x * 256 + threadIdx.x;   // one per (b,n), total B*N = 131072
    int b = gid >> 16;
    const float* cp = coords + (size_t)gid * 3;
    float cx = cp[0], cy = cp[1], cz = cp[2];
    const float* cb = coords + (size_t)b * (N_PTS * 3);
    const int* ip = knn + ((size_t)gid << 4);
    const float* dp = dist + ((size_t)gid << 4);

    float s[35];
#pragma unroll
    for (int i = 0; i < 35; i++) s[i] = 0.f;

    for (int k = 0; k < KNN; k++) {
        int idx = ip[k];
        const float* q = cb + (size_t)idx * 3;
        float v[7];
        v[0] = cx; v[1] = cy; v[2] = cz;
        v[3] = q[0]; v[4] = q[1]; v[5] = q[2];
        v[6] = dp[k];
        int t = 7;
#pragma unroll
        for (int i = 0; i < 7; i++) {
            s[i] += v[i];
#pragma unroll
            for (int j = i; j < 7; j++) { s[t] += v[i] * v[j]; t++; }
        }
    }

    __shared__ float red[4][35];
    int lane = threadIdx.x & 63;
    int wid  = threadIdx.x >> 6;
#pragma unroll
    for (int i = 0; i < 35; i++) {
        float v = s[i];
#pragma unroll
        for (int off = 32; off; off >>= 1) v += __shfl_xor(v, off);
        if (lane == 0) red[wid][i] = v;
    }
    __syncthreads();
    if (threadIdx.x < 35) {
        int i = threadIdx.x;
        float v = (red[0][i] + red[1][i]) + (red[2][i] + red[3][i]);
        if (use_part) partials[i * NBLK_STATS + blockIdx.x] = v;
        else          atomicAdd(&stats_atomic[i], v);   // 512 blocks x 35 only
    }
}

// ---- Prep: reduce partials, fold BN into per-channel affine w8 ----
__global__ __launch_bounds__(64) void k_prep(const float* __restrict__ W,
                                             const float* __restrict__ bias,
                                             const float* __restrict__ gamma,
                                             const float* __restrict__ beta,
                                             const float* __restrict__ stats_atomic,
                                             const float* __restrict__ partials,
                                             int use_part,
                                             float* __restrict__ w8) {
    __shared__ float sst[35];
    int t = threadIdx.x;
    if (t < 35) {
        if (use_part) {
            const float* p = partials + t * NBLK_STATS;
            float a0 = 0.f, a1 = 0.f, a2 = 0.f, a3 = 0.f;
            for (int j = 0; j < NBLK_STATS; j += 4) {
                a0 += p[j]; a1 += p[j + 1]; a2 += p[j + 2]; a3 += p[j + 3];
            }
            sst[t] = (a0 + a1) + (a2 + a3);
        } else {
            sst[t] = stats_atomic[t];
        }
    }
    __syncthreads();

    int o = t; // 0..63
    const float invM = 1.0f / (float)((size_t)BATCH * N_PTS * KNN);
    float m[7];
#pragma unroll
    for (int j = 0; j < 7; j++) m[j] = sst[j] * invM;
    const float* Wo = W + o * 10;
    float wv[7];
    wv[0] = Wo[0] + Wo[6]; wv[1] = Wo[1] + Wo[7]; wv[2] = Wo[2] + Wo[8];
    wv[3] = Wo[3] - Wo[6]; wv[4] = Wo[4] - Wo[7]; wv[5] = Wo[5] - Wo[8];
    wv[6] = Wo[9];
    float mean = bias[o];
#pragma unroll
    for (int j = 0; j < 7; j++) mean += wv[j] * m[j];
    float var = 0.f;
#pragma unroll
    for (int i = 0; i < 7; i++) {
#pragma unroll
        for (int j = 0; j < 7; j++) {
            int a = i < j ? i : j, c = i < j ? j : i;
            float cov = sst[7 + tri(a, c)] * invM - m[i] * m[j];
            var += wv[i] * wv[j] * cov;
        }
    }
    float s = gamma[o] * rsqrtf(var + 1e-6f);
    float sh = beta[o] - mean * s;        // out = s*x + sh, x = wv.v + b_o
#pragma unroll
    for (int j = 0; j < 7; j++) w8[o * 8 + j] = s * wv[j];
    w8[o * 8 + 7] = s * bias[o] + sh;     // fold bias into constant
}

// ---- Pass 2: x channels [B,0..63,N,K]; 4 threads/point (k-quad each);
//      per store instruction: lane l writes bytes [16l,16l+16) = contiguous 1KB ----
__global__ __launch_bounds__(256) void k_x(const float* __restrict__ coords,
                                           const int* __restrict__ knn,
                                           const float* __restrict__ dist,
                                           const float* __restrict__ w8g,
                                           float* __restrict__ out) {
    __shared__ float w8[512];
    for (int i = threadIdx.x; i < 512; i += 256) w8[i] = w8g[i];
    __syncthreads();

    int gid = blockIdx.x * 256 + threadIdx.x;   // B*N*4 threads
    int q  = gid & 3;                            // k-quad: k = 4q..4q+3
    int pp = gid >> 2;                           // b*N + n
    int b = pp >> 16;
    int n = pp & 0xFFFF;

    const float* cp = coords + (size_t)pp * 3;
    float cx = cp[0], cy = cp[1], cz = cp[2];
    const float* cb = coords + (size_t)b * (N_PTS * 3);

    // unit-stride 16B/lane loads: int4/float4 at (pp*16 + 4q)
    int4   ia = *(const int4*)  (knn  + ((size_t)pp << 4) + (q << 2));
    float4 da = *(const float4*)(dist + ((size_t)pp << 4) + (q << 2));
    int   idx[4] = {ia.x, ia.y, ia.z, ia.w};
    float dd[4]  = {da.x, da.y, da.z, da.w};
    float nx[4], ny[4], nz[4];
#pragma unroll
    for (int k = 0; k < 4; k++) {
        const float* qq = cb + (size_t)idx[k] * 3;
        nx[k] = qq[0]; ny[k] = qq[1]; nz[k] = qq[2];
    }

    size_t base = ((size_t)b * 128) * (N_PTS * KNN) + (size_t)n * KNN + (q << 2);
#pragma unroll 4
    for (int c = 0; c < 64; c++) {
        float4 wa = *reinterpret_cast<const float4*>(&w8[c << 3]);      // ds_read_b128
        float4 wb = *reinterpret_cast<const float4*>(&w8[(c << 3) + 4]);
        float s0 = fmaf(cx, wa.x, fmaf(cy, wa.y, fmaf(cz, wa.z, wb.w)));
        float x[4];
#pragma unroll
        for (int k = 0; k < 4; k++) {
            float v = fmaf(dd[k], wb.z, fmaf(nz[k], wb.y, fmaf(ny[k], wb.x, fmaf(nx[k], wa.w, s0))));
            x[k] = fmaxf(v, 0.f);
        }
        float4n v0 = {x[0], x[1], x[2], x[3]};
        __builtin_nontemporal_store(v0,
            reinterpret_cast<float4n*>(out + base + (size_t)c * (N_PTS * KNN)));
    }
}

// ---- Pass 3: feature broadcast [B,64..127,N,K], f32 out, NT stores (r5 version) ----
__global__ __launch_bounds__(256) void k_feat(const float* __restrict__ feat,
                                              float* __restrict__ out) {
    int gid = blockIdx.x * 256 + threadIdx.x;  // B*64*N*2 threads
    int h = gid & 1;
    int q = gid >> 1;                          // (b*64+f)*N + n
    float v = feat[q];
    int b = q >> 22;
    int f = (q >> 16) & 63;
    int n = q & 0xFFFF;
    size_t base = (((size_t)b * 128 + 64 + f) * N_PTS + n) * KNN + (h << 3);
    float4n vv = {v, v, v, v};
    __builtin_nontemporal_store(vv, reinterpret_cast<float4n*>(out + base));
    __builtin_nontemporal_store(vv, reinterpret_cast<float4n*>(out + base + 4));
}

extern "C" void kernel_launch(void* const* d_in, const int* in_sizes, int n_in,
                              void* d_out, int out_size, void* d_ws, size_t ws_size,
                              hipStream_t stream) {
    const float* coords   = (const float*)d_in[0];
    const float* features = (const float*)d_in[1];
    const int*   knn      = (const int*)d_in[2];
    const float* dist     = (const float*)d_in[3];
    const float* W        = (const float*)d_in[4];
    const float* bias     = (const float*)d_in[5];
    const float* gamma    = (const float*)d_in[6];
    const float* beta     = (const float*)d_in[7];
    float* out            = (float*)d_out;

    // ws layout: stats[64] | w8[512] | partials[35*512]
    float* stats    = (float*)d_ws;
    float* w8       = stats + 64;
    float* partials = w8 + 512;
    size_t need = (64 + 512 + 35 * NBLK_STATS) * sizeof(float);
    int use_part = (ws_size >= need) ? 1 : 0;

    (void)hipMemsetAsync(d_ws, 0, 64 * sizeof(float), stream);  // only atomic path needs it
    k_stats<<<NBLK_STATS, 256, 0, stream>>>(coords, knn, dist, stats, partials, use_part);
    k_prep<<<1, 64, 0, stream>>>(W, bias, gamma, beta, stats, partials, use_part, w8);
    k_x<<<2048, 256, 0, stream>>>(coords, knn, dist, w8, out);
    k_feat<<<65536, 256, 0, stream>>>(features, out);
}

// Round 9
// 237.980 us; speedup vs baseline: 3.1671x; 1.5865x over previous
//
#include <hip/hip_runtime.h>
#include <hip/hip_bf16.h>

#define N_PTS 65536
#define BATCH 2
#define KNN   16
#define NBLK_STATS 512

typedef float float4n __attribute__((ext_vector_type(4)));

__device__ __forceinline__ int tri(int i, int j) { // i<=j, 7x7 upper triangle
    return i * 7 - (i * (i - 1)) / 2 + (j - i);
}

// ---- Pass 1: moments of v=(cx,cy,cz,nx,ny,nz,d); per-block partials, no contended atomics ----
__global__ __launch_bounds__(256) void k_stats(const float* __restrict__ coords,
                                               const int* __restrict__ knn,
                                               const float* __restrict__ dist,
                                               float* __restrict__ stats_atomic,
                                               float* __restrict__ partials,
                                               int use_part) {
    int gid = blockIdx.x * 256 + threadIdx.x;   // one per (b,n), total B*N = 131072
    int b = gid >> 16;
    const float* cp = coords + (size_t)gid * 3;
    float cx = cp[0], cy = cp[1], cz = cp[2];
    const float* cb = coords + (size_t)b * (N_PTS * 3);
    const int* ip = knn + ((size_t)gid << 4);
    const float* dp = dist + ((size_t)gid << 4);

    float s[35];
#pragma unroll
    for (int i = 0; i < 35; i++) s[i] = 0.f;

    for (int k = 0; k < KNN; k++) {
        int idx = ip[k];
        const float* q = cb + (size_t)idx * 3;
        float v[7];
        v[0] = cx; v[1] = cy; v[2] = cz;
        v[3] = q[0]; v[4] = q[1]; v[5] = q[2];
        v[6] = dp[k];
        int t = 7;
#pragma unroll
        for (int i = 0; i < 7; i++) {
            s[i] += v[i];
#pragma unroll
            for (int j = i; j < 7; j++) { s[t] += v[i] * v[j]; t++; }
        }
    }

    __shared__ float red[4][35];
    int lane = threadIdx.x & 63;
    int wid  = threadIdx.x >> 6;
#pragma unroll
    for (int i = 0; i < 35; i++) {
        float v = s[i];
#pragma unroll
        for (int off = 32; off; off >>= 1) v += __shfl_xor(v, off);
        if (lane == 0) red[wid][i] = v;
    }
    __syncthreads();
    if (threadIdx.x < 35) {
        int i = threadIdx.x;
        float v = (red[0][i] + red[1][i]) + (red[2][i] + red[3][i]);
        if (use_part) partials[i * NBLK_STATS + blockIdx.x] = v;
        else          atomicAdd(&stats_atomic[i], v);   // 512 blocks x 35 only
    }
}

// ---- Prep: reduce partials, fold BN into per-channel affine w8 ----
__global__ __launch_bounds__(64) void k_prep(const float* __restrict__ W,
                                             const float* __restrict__ bias,
                                             const float* __restrict__ gamma,
                                             const float* __restrict__ beta,
                                             const float* __restrict__ stats_atomic,
                                             const float* __restrict__ partials,
                                             int use_part,
                                             float* __restrict__ w8) {
    __shared__ float sst[35];
    int t = threadIdx.x;
    if (t < 35) {
        if (use_part) {
            const float* p = partials + t * NBLK_STATS;
            float a0 = 0.f, a1 = 0.f, a2 = 0.f, a3 = 0.f;
            for (int j = 0; j < NBLK_STATS; j += 4) {
                a0 += p[j]; a1 += p[j + 1]; a2 += p[j + 2]; a3 += p[j + 3];
            }
            sst[t] = (a0 + a1) + (a2 + a3);
        } else {
            sst[t] = stats_atomic[t];
        }
    }
    __syncthreads();

    int o = t; // 0..63
    const float invM = 1.0f / (float)((size_t)BATCH * N_PTS * KNN);
    float m[7];
#pragma unroll
    for (int j = 0; j < 7; j++) m[j] = sst[j] * invM;
    const float* Wo = W + o * 10;
    float wv[7];
    wv[0] = Wo[0] + Wo[6]; wv[1] = Wo[1] + Wo[7]; wv[2] = Wo[2] + Wo[8];
    wv[3] = Wo[3] - Wo[6]; wv[4] = Wo[4] - Wo[7]; wv[5] = Wo[5] - Wo[8];
    wv[6] = Wo[9];
    float mean = bias[o];
#pragma unroll
    for (int j = 0; j < 7; j++) mean += wv[j] * m[j];
    float var = 0.f;
#pragma unroll
    for (int i = 0; i < 7; i++) {
#pragma unroll
        for (int j = 0; j < 7; j++) {
            int a = i < j ? i : j, c = i < j ? j : i;
            float cov = sst[7 + tri(a, c)] * invM - m[i] * m[j];
            var += wv[i] * wv[j] * cov;
        }
    }
    float s = gamma[o] * rsqrtf(var + 1e-6f);
    float sh = beta[o] - mean * s;        // out = s*x + sh, x = wv.v + b_o
#pragma unroll
    for (int j = 0; j < 7; j++) w8[o * 8 + j] = s * wv[j];
    w8[o * 8 + 7] = s * bias[o] + sh;     // fold bias into constant
}

// ---- Pass 2: x channels [B,0..63,N,K]; 4 threads/point (k-quad each);
//      per store instruction: lane l writes bytes [16l,16l+16) = contiguous 1KB ----
__global__ __launch_bounds__(256) void k_x(const float* __restrict__ coords,
                                           const int* __restrict__ knn,
                                           const float* __restrict__ dist,
                                           const float* __restrict__ w8g,
                                           float* __restrict__ out) {
    __shared__ float w8[512];
    for (int i = threadIdx.x; i < 512; i += 256) w8[i] = w8g[i];
    __syncthreads();

    int gid = blockIdx.x * 256 + threadIdx.x;   // B*N*4 threads
    int q  = gid & 3;                            // k-quad: k = 4q..4q+3
    int pp = gid >> 2;                           // b*N + n
    int b = pp >> 16;
    int n = pp & 0xFFFF;

    const float* cp = coords + (size_t)pp * 3;
    float cx = cp[0], cy = cp[1], cz = cp[2];
    const float* cb = coords + (size_t)b * (N_PTS * 3);

    // unit-stride 16B/lane loads: int4/float4 at (pp*16 + 4q)
    int4   ia = *(const int4*)  (knn  + ((size_t)pp << 4) + (q << 2));
    float4 da = *(const float4*)(dist + ((size_t)pp << 4) + (q << 2));
    int   idx[4] = {ia.x, ia.y, ia.z, ia.w};
    float dd[4]  = {da.x, da.y, da.z, da.w};
    float nx[4], ny[4], nz[4];
#pragma unroll
    for (int k = 0; k < 4; k++) {
        const float* qq = cb + (size_t)idx[k] * 3;
        nx[k] = qq[0]; ny[k] = qq[1]; nz[k] = qq[2];
    }

    size_t base = ((size_t)b * 128) * (N_PTS * KNN) + (size_t)n * KNN + (q << 2);
#pragma unroll 4
    for (int c = 0; c < 64; c++) {
        float4 wa = *reinterpret_cast<const float4*>(&w8[c << 3]);      // ds_read_b128
        float4 wb = *reinterpret_cast<const float4*>(&w8[(c << 3) + 4]);
        float s0 = fmaf(cx, wa.x, fmaf(cy, wa.y, fmaf(cz, wa.z, wb.w)));
        float x[4];
#pragma unroll
        for (int k = 0; k < 4; k++) {
            float v = fmaf(dd[k], wb.z, fmaf(nz[k], wb.y, fmaf(ny[k], wb.x, fmaf(nx[k], wa.w, s0))));
            x[k] = fmaxf(v, 0.f);
        }
        float4n v0 = {x[0], x[1], x[2], x[3]};
        __builtin_nontemporal_store(v0,
            reinterpret_cast<float4n*>(out + base + (size_t)c * (N_PTS * KNN)));
    }
}

// ---- Pass 3: feature broadcast [B,64..127,N,K]; 4 threads/(b,f,n), one k-quad each;
//      per store instruction: lane l writes bytes [16l,16l+16) = contiguous 1KB ----
__global__ __launch_bounds__(256) void k_feat(const float* __restrict__ feat,
                                              float* __restrict__ out) {
    int gid = blockIdx.x * 256 + threadIdx.x;  // B*64*N*4 = 33,554,432 threads
    int q4 = gid & 3;                          // k-quad
    int r  = gid >> 2;                         // (b*64+f)*N + n
    float v = feat[r];
    int b = r >> 22;
    int f = (r >> 16) & 63;
    int n = r & 0xFFFF;
    size_t base = (((size_t)b * 128 + 64 + f) * N_PTS + n) * KNN + (q4 << 2);
    float4n vv = {v, v, v, v};
    __builtin_nontemporal_store(vv, reinterpret_cast<float4n*>(out + base));
}

extern "C" void kernel_launch(void* const* d_in, const int* in_sizes, int n_in,
                              void* d_out, int out_size, void* d_ws, size_t ws_size,
                              hipStream_t stream) {
    const float* coords   = (const float*)d_in[0];
    const float* features = (const float*)d_in[1];
    const int*   knn      = (const int*)d_in[2];
    const float* dist     = (const float*)d_in[3];
    const float* W        = (const float*)d_in[4];
    const float* bias     = (const float*)d_in[5];
    const float* gamma    = (const float*)d_in[6];
    const float* beta     = (const float*)d_in[7];
    float* out            = (float*)d_out;

    // ws layout: stats[64] | w8[512] | partials[35*512]
    float* stats    = (float*)d_ws;
    float* w8       = stats + 64;
    float* partials = w8 + 512;
    size_t need = (64 + 512 + 35 * NBLK_STATS) * sizeof(float);
    int use_part = (ws_size >= need) ? 1 : 0;

    (void)hipMemsetAsync(d_ws, 0, 64 * sizeof(float), stream);  // only atomic path needs it
    k_stats<<<NBLK_STATS, 256, 0, stream>>>(coords, knn, dist, stats, partials, use_part);
    k_prep<<<1, 64, 0, stream>>>(W, bias, gamma, beta, stats, partials, use_part, w8);
    k_x<<<2048, 256, 0, stream>>>(coords, knn, dist, w8, out);
    k_feat<<<131072, 256, 0, stream>>>(features, out);
}